// Round 8
// baseline (485.071 us; speedup 1.0000x reference)
//
#include <hip/hip_runtime.h>

typedef unsigned short u16;
typedef __attribute__((ext_vector_type(8))) short short8;
typedef __attribute__((ext_vector_type(8))) __bf16 bf16x8;
typedef __attribute__((ext_vector_type(4))) float floatx4;

#define BATCH 128
#define SEQ 197
#define CH 768
#define NH 12
#define HD 64
#define MROWS (BATCH * SEQ)   // 25216
#define MPAD 25344            // 99 * 256
#define QKVC (3 * CH)         // 2304

#define TMR 256
#define BK 64
#define NKT (CH / BK)         // 12
#define KSSZ 16384            // u16: one kslot sub-tile (A 256x32 + B 256x32)
#define BUFSZ 32768           // u16: 2 kslots

__device__ __forceinline__ floatx4 mfma16(short8 a, short8 b, floatx4 c) {
  return __builtin_amdgcn_mfma_f32_16x16x32_bf16(
      __builtin_bit_cast(bf16x8, a), __builtin_bit_cast(bf16x8, b), c, 0, 0, 0);
}

__device__ __forceinline__ u16 f2bf(float f) {
  unsigned u = __builtin_bit_cast(unsigned, f);
  return (u16)((u + 0x7fffu + ((u >> 16) & 1u)) >> 16);
}

__device__ __forceinline__ void async16(const u16* g, u16* s) {
  __builtin_amdgcn_global_load_lds((const __attribute__((address_space(1))) void*)g,
                                   (__attribute__((address_space(3))) void*)s, 16, 0, 0);
}

// ---------------- fused preprocessing: 3x fp32->bf16 + relb gather + pad zeroing ----------------
__global__ __launch_bounds__(256) void preproc(const float4* __restrict__ x, ushort4* __restrict__ xo, int n0,
                                               const float4* __restrict__ w1, ushort4* __restrict__ w1o, int n1,
                                               const float4* __restrict__ w2, ushort4* __restrict__ w2o, int n2,
                                               const int* __restrict__ idx, const float* __restrict__ table,
                                               float* __restrict__ relb, ushort4* __restrict__ ao4) {
  int i = blockIdx.x * 256 + threadIdx.x;
  const float4* in; ushort4* out; int j;
  if (i < n0) { in = x; out = xo; j = i; }
  else if (i < n0 + n1) { in = w1; out = w1o; j = i - n0; }
  else if (i < n0 + n1 + n2) { in = w2; out = w2o; j = i - n0 - n1; }
  else {
    int t = i - (n0 + n1 + n2);
    const int npad = (MPAD - MROWS) * CH / 4;
    if (t < SEQ * SEQ) {
      int id = idx[t];
      const float* row = table + id * NH;
#pragma unroll
      for (int h = 0; h < NH; h++) relb[h * (SEQ * SEQ) + t] = row[h];
    } else if (t < SEQ * SEQ + npad) {
      ushort4 z = {0, 0, 0, 0};
      xo[n0 + (t - SEQ * SEQ)] = z;                       // x_bf pad rows
    } else if (t < SEQ * SEQ + 2 * npad) {
      ushort4 z = {0, 0, 0, 0};
      ao4[(size_t)MROWS * CH / 4 + (t - SEQ * SEQ - npad)] = z;  // ao_bf pad rows
    }
    return;
  }
  float4 v = in[j];
  ushort4 o;
  o.x = f2bf(v.x); o.y = f2bf(v.y); o.z = f2bf(v.z); o.w = f2bf(v.w);
  out[j] = o;
}

// ---- 256x256x64 8-wave 4-phase GEMM core with counted vmcnt + B-register retention ----
// LDS per kslot: A[256][32] + B[256][32] u16, granule swizzle phys = logical ^ ((row>>1)&3)
// (identical algebra to the measured-0-conflict R6 layout). Staged linearly with
// pre-swizzled per-lane global source; counted vmcnt(4) gates at ph0/ph1 only.

#define STAGE_KS(buf_, ks_, kk_)                                               \
  do {                                                                         \
    u16* d_ = Sb + (buf_)*BUFSZ + (ks_)*KSSZ;                                  \
    async16(sA0 + (kk_) + (ks_)*32, d_ + dO0);                                 \
    async16(sA1 + (kk_) + (ks_)*32, d_ + dO1);                                 \
    async16(sB0 + (kk_) + (ks_)*32, d_ + 8192 + dO0);                          \
    async16(sB1 + (kk_) + (ks_)*32, d_ + 8192 + dO1);                          \
  } while (0)

#define LOAD_A(mh_, ks_)                                                       \
  do {                                                                         \
    const u16* ab_ = Sb + rb * BUFSZ + (ks_)*KSSZ;                             \
    _Pragma("unroll")                                                          \
    for (int i_ = 0; i_ < 4; i_++)                                             \
      af[i_] = *(const short8*)(ab_ + (wm * 128 + (mh_)*64 + i_ * 16 + c16) * 32 + fsl); \
  } while (0)

#define LOAD_B(dst_, ks_)                                                      \
  do {                                                                         \
    const u16* bb_ = Sb + rb * BUFSZ + (ks_)*KSSZ + 8192;                      \
    _Pragma("unroll")                                                          \
    for (int j_ = 0; j_ < 4; j_++)                                             \
      dst_[j_] = *(const short8*)(bb_ + (wn * 64 + j_ * 16 + c16) * 32 + fsl); \
  } while (0)

#define MFMA16X(mh_, bfr_)                                                     \
  do {                                                                         \
    __builtin_amdgcn_s_setprio(1);                                             \
    _Pragma("unroll")                                                          \
    for (int i_ = 0; i_ < 4; i_++)                                             \
      _Pragma("unroll")                                                        \
      for (int j_ = 0; j_ < 4; j_++)                                           \
        acc[(mh_)*4 + i_][j_] = mfma16(af[i_], bfr_[j_], acc[(mh_)*4 + i_][j_]); \
    __builtin_amdgcn_s_setprio(0);                                             \
  } while (0)

#define GEMM_CORE(Amat_, Wmat_, NBLK_)                                         \
  __shared__ u16 Sb[2 * BUFSZ]; /* 128 KB */                                   \
  int tid = threadIdx.x;                                                       \
  int wave = tid >> 6, lane = tid & 63, quad = lane >> 4, c16 = lane & 15;     \
  int wm = wave >> 2, wn = wave & 3;                                           \
  int nwg = gridDim.x;                                                         \
  int orig = blockIdx.x;                                                       \
  int xcd = orig & 7, pos = orig >> 3;                                         \
  int qq = nwg >> 3, rr = nwg & 7;                                             \
  int lid = (xcd < rr ? xcd * (qq + 1) : rr * (qq + 1) + (xcd - rr) * qq) + pos; \
  int mblk = lid / (NBLK_), nblk = lid - mblk * (NBLK_);                       \
  int m0 = mblk * TMR, n0 = nblk * TMR;                                        \
  int L0 = tid, L1 = 512 + tid;                                                \
  int rL0 = L0 >> 2, gL0 = (L0 & 3) ^ ((rL0 >> 1) & 3);                        \
  int rL1 = L1 >> 2, gL1 = (L1 & 3) ^ ((rL1 >> 1) & 3);                        \
  const u16* sA0 = (Amat_) + (size_t)(m0 + rL0) * CH + gL0 * 8;                \
  const u16* sA1 = (Amat_) + (size_t)(m0 + rL1) * CH + gL1 * 8;                \
  const u16* sB0 = (Wmat_) + (size_t)(n0 + rL0) * CH + gL0 * 8;                \
  const u16* sB1 = (Wmat_) + (size_t)(n0 + rL1) * CH + gL1 * 8;                \
  int dO0 = wave * 512;                                                        \
  int dO1 = 4096 + wave * 512;                                                 \
  int fsl = (quad ^ ((c16 >> 1) & 3)) * 8;                                     \
  floatx4 acc[8][4] = {};                                                      \
  STAGE_KS(0, 0, 0);                                                           \
  STAGE_KS(0, 1, 0);                                                           \
  for (int kt = 0; kt < NKT; ++kt) {                                           \
    int rb = kt & 1, sb = rb ^ 1;                                              \
    int kkn = (kt + 1 < NKT ? kt + 1 : NKT - 1) * BK;                          \
    short8 af[4], b0f[4], b1f[4];                                              \
    /* PH0: gate ks0(kt), stage ks0(next), compute mh0 x ks0 */                \
    asm volatile("s_waitcnt vmcnt(4)" ::: "memory");                           \
    __builtin_amdgcn_s_barrier();                                              \
    asm volatile("" ::: "memory");                                             \
    STAGE_KS(sb, 0, kkn);                                                      \
    LOAD_A(0, 0); LOAD_B(b0f, 0);                                              \
    MFMA16X(0, b0f);                                                           \
    /* PH1: gate ks1(kt), stage ks1(next), compute mh0 x ks1 */                \
    asm volatile("s_waitcnt vmcnt(4)" ::: "memory");                           \
    __builtin_amdgcn_s_barrier();                                              \
    asm volatile("" ::: "memory");                                             \
    STAGE_KS(sb, 1, kkn);                                                      \
    LOAD_A(0, 1); LOAD_B(b1f, 1);                                              \
    MFMA16X(0, b1f);                                                           \
    /* PH2: compute mh1 x ks0 (B retained in regs) */                          \
    asm volatile("" ::: "memory");                                             \
    __builtin_amdgcn_s_barrier();                                              \
    asm volatile("" ::: "memory");                                             \
    LOAD_A(1, 0);                                                              \
    MFMA16X(1, b0f);                                                           \
    /* PH3: compute mh1 x ks1 */                                               \
    asm volatile("" ::: "memory");                                             \
    __builtin_amdgcn_s_barrier();                                              \
    asm volatile("" ::: "memory");                                             \
    LOAD_A(1, 1);                                                              \
    MFMA16X(1, b1f);                                                           \
  }                                                                            \
  asm volatile("s_waitcnt vmcnt(0)" ::: "memory");

// ---------------- QKV GEMM: grid 99*9=891, block 512, unified qkv[M][2304] out ----------------
__global__ __launch_bounds__(512, 1) void gemm_qkv(const u16* __restrict__ A,
                                                   const u16* __restrict__ W,
                                                   const float* __restrict__ qb,
                                                   const float* __restrict__ vb,
                                                   u16* __restrict__ qkv) {
  GEMM_CORE(A, W, 9)

#pragma unroll
  for (int j = 0; j < 4; j++) {
    int gcol = n0 + wn * 64 + j * 16 + c16;   // 0..2303
    float badd = (gcol < CH) ? qb[gcol] : (gcol >= 2 * CH ? vb[gcol - 2 * CH] : 0.0f);
#pragma unroll
    for (int mi = 0; mi < 8; mi++) {
#pragma unroll
      for (int r = 0; r < 4; r++) {
        int grow = m0 + wm * 128 + (mi >> 2) * 64 + (mi & 3) * 16 + quad * 4 + r;
        if (grow < MROWS)
          qkv[(size_t)grow * QKVC + gcol] = f2bf(acc[mi][j][r] + badd);
      }
    }
  }
}

// ---------------- proj GEMM: grid 99*3=297, block 512, fp32 out ----------------
__global__ __launch_bounds__(512, 1) void gemm_proj(const u16* __restrict__ A,
                                                    const u16* __restrict__ W,
                                                    const float* __restrict__ bias,
                                                    float* __restrict__ out) {
  GEMM_CORE(A, W, 3)

#pragma unroll
  for (int j = 0; j < 4; j++) {
    int gcol = n0 + wn * 64 + j * 16 + c16;
    float bj = bias[gcol];
#pragma unroll
    for (int mi = 0; mi < 8; mi++) {
#pragma unroll
      for (int r = 0; r < 4; r++) {
        int grow = m0 + wm * 128 + (mi >> 2) * 64 + (mi & 3) * 16 + quad * 4 + r;
        if (grow < MROWS)
          out[(size_t)grow * CH + gcol] = acc[mi][j][r] + bj;
      }
    }
  }
}

// ---------------- attention: one block per (h, b), register softmax, deferred 1/sum ----------------
#define PS 232
#define VS 264

__global__ __launch_bounds__(256, 2) void attn(const u16* __restrict__ qkv,
                                               const float* __restrict__ relb,
                                               u16* __restrict__ attn_out) {
  __shared__ u16 Vt[64 * VS];
  __shared__ u16 P[4 * 16 * PS];

  int h = blockIdx.x, b = blockIdx.y;
  int tid = threadIdx.x, wave = tid >> 6, lane = tid & 63, quad = lane >> 4, c16 = lane & 15;
  const u16* Q = qkv + (size_t)b * SEQ * QKVC + h * HD;
  const u16* Kp = Q + CH;
  const u16* Vp = Q + 2 * CH;
  const float* RB = relb + (size_t)h * (SEQ * SEQ);

  {
    int mrow = tid >> 3, dbase = (tid & 7) * 8;
#pragma unroll
    for (int i = 0; i < 7; i++) {
      int m = mrow + 32 * i;
      if (m < SEQ) {
        ushort4 v0 = *(const ushort4*)(Vp + (size_t)m * QKVC + dbase);
        ushort4 v1 = *(const ushort4*)(Vp + (size_t)m * QKVC + dbase + 4);
        Vt[(dbase + 0) * VS + m] = v0.x;
        Vt[(dbase + 1) * VS + m] = v0.y;
        Vt[(dbase + 2) * VS + m] = v0.z;
        Vt[(dbase + 3) * VS + m] = v0.w;
        Vt[(dbase + 4) * VS + m] = v1.x;
        Vt[(dbase + 5) * VS + m] = v1.y;
        Vt[(dbase + 6) * VS + m] = v1.z;
        Vt[(dbase + 7) * VS + m] = v1.w;
      } else {
#pragma unroll
        for (int dd = 0; dd < 8; dd++) Vt[(dbase + dd) * VS + m] = 0;
      }
    }
  }
  __syncthreads();

  u16* Pw = P + wave * 16 * PS;
  for (int rt = wave; rt < 13; rt += 4) {
    int q0 = rt * 16;
    int qr = min(q0 + c16, SEQ - 1);
    short8 qa0 = *(const short8*)(Q + (size_t)qr * QKVC + quad * 8);
    short8 qa1 = *(const short8*)(Q + (size_t)qr * QKVC + 32 + quad * 8);

    floatx4 sacc[13];
    __builtin_amdgcn_s_setprio(1);
#pragma unroll
    for (int nt = 0; nt < 13; nt++) {
      int mc = min(nt * 16 + c16, SEQ - 1);
      floatx4 a = {0.f, 0.f, 0.f, 0.f};
      a = mfma16(qa0, *(const short8*)(Kp + (size_t)mc * QKVC + quad * 8), a);
      a = mfma16(qa1, *(const short8*)(Kp + (size_t)mc * QKVC + 32 + quad * 8), a);
      sacc[nt] = a;
    }
    __builtin_amdgcn_s_setprio(0);

    float invr[4];
#pragma unroll
    for (int r = 0; r < 4; r++) {
      int rq = min(q0 + quad * 4 + r, SEQ - 1);
      const float* RBr = RB + (size_t)rq * SEQ;
      float mx = -1e30f;
#pragma unroll
      for (int nt = 0; nt < 13; nt++) {
        int m = nt * 16 + c16;
        float s = -1e30f;
        if (m < SEQ) s = sacc[nt][r] * 0.125f + RBr[m];
        sacc[nt][r] = s;
        mx = fmaxf(mx, s);
      }
      mx = fmaxf(mx, __shfl_xor(mx, 1));
      mx = fmaxf(mx, __shfl_xor(mx, 2));
      mx = fmaxf(mx, __shfl_xor(mx, 4));
      mx = fmaxf(mx, __shfl_xor(mx, 8));
      float sum = 0.f;
#pragma unroll
      for (int nt = 0; nt < 13; nt++) {
        float e = __expf(sacc[nt][r] - mx);
        sacc[nt][r] = e;
        sum += e;
      }
      sum += __shfl_xor(sum, 1);
      sum += __shfl_xor(sum, 2);
      sum += __shfl_xor(sum, 4);
      sum += __shfl_xor(sum, 8);
      invr[r] = 1.f / sum;
      int prow = (quad * 4 + r) * PS;
#pragma unroll
      for (int nt = 0; nt < 13; nt++)
        Pw[prow + nt * 16 + c16] = f2bf(sacc[nt][r]);   // unnormalized (e <= 1)
      Pw[prow + 208 + c16] = 0;
    }

    floatx4 oacc[4] = {};
    __builtin_amdgcn_s_setprio(1);
#pragma unroll
    for (int ks = 0; ks < 7; ks++) {
      short8 a = *(const short8*)(Pw + c16 * PS + ks * 32 + quad * 8);
#pragma unroll
      for (int dt = 0; dt < 4; dt++) {
        short8 bb = *(const short8*)(Vt + (dt * 16 + c16) * VS + ks * 32 + quad * 8);
        oacc[dt] = mfma16(a, bb, oacc[dt]);
      }
    }
    __builtin_amdgcn_s_setprio(0);
#pragma unroll
    for (int dt = 0; dt < 4; dt++) {
      int d = dt * 16 + c16;
#pragma unroll
      for (int r = 0; r < 4; r++) {
        int grow = q0 + quad * 4 + r;
        if (grow < SEQ)
          attn_out[((size_t)b * SEQ + grow) * CH + h * HD + d] = f2bf(oacc[dt][r] * invr[r]);
      }
    }
  }
}

extern "C" void kernel_launch(void* const* d_in, const int* in_sizes, int n_in,
                              void* d_out, int out_size, void* d_ws, size_t ws_size,
                              hipStream_t stream) {
  const float* x      = (const float*)d_in[0];
  const float* qkv_w  = (const float*)d_in[1];
  const float* q_bias = (const float*)d_in[2];
  const float* v_bias = (const float*)d_in[3];
  const float* table  = (const float*)d_in[4];
  const float* proj_w = (const float*)d_in[5];
  const float* proj_b = (const float*)d_in[6];
  const int*   rel_ix = (const int*)d_in[7];
  float* out = (float*)d_out;

  char* ws = (char*)d_ws;
  size_t off = 0;
  u16* x_bf    = (u16*)(ws + off); off += (size_t)MPAD * CH * 2;
  u16* wq_bf   = (u16*)(ws + off); off += (size_t)3 * CH * CH * 2;
  u16* wp_bf   = (u16*)(ws + off); off += (size_t)CH * CH * 2;
  u16* qkv_buf = (u16*)(ws + off); off += (size_t)MROWS * QKVC * 2;
  u16* ao_bf   = (u16*)(ws + off); off += (size_t)MPAD * CH * 2;
  float* relb  = (float*)(ws + off);

  int n0 = MROWS * CH / 4;
  int n1 = 3 * CH * CH / 4;
  int n2 = CH * CH / 4;
  int npad = (MPAD - MROWS) * CH / 4;
  int ntot = n0 + n1 + n2 + SEQ * SEQ + 2 * npad;
  preproc<<<(ntot + 255) / 256, 256, 0, stream>>>(
      (const float4*)x, (ushort4*)x_bf, n0,
      (const float4*)qkv_w, (ushort4*)wq_bf, n1,
      (const float4*)proj_w, (ushort4*)wp_bf, n2,
      rel_ix, table, relb, (ushort4*)ao_bf);
  gemm_qkv<<<dim3(99 * 9), 512, 0, stream>>>(x_bf, wq_bf, q_bias, v_bias, qkv_buf);
  attn<<<dim3(NH, BATCH), 256, 0, stream>>>(qkv_buf, relb, ao_bf);
  gemm_proj<<<dim3(99 * 3), 512, 0, stream>>>(ao_bf, wp_bf, proj_b, out);
}